// Round 4
// baseline (403.819 us; speedup 1.0000x reference)
//
#include <hip/hip_runtime.h>
#include <hip/hip_bf16.h>

typedef _Float16 half8 __attribute__((ext_vector_type(8)));
typedef float floatx4 __attribute__((ext_vector_type(4)));

#define D_MODEL 1024
#define NHEAD   16
#define DH      64
#define BATCH   2
#define SEQ     2048
#define M_TOT   4096   // BATCH*SEQ

__device__ inline half8 pack8(float4 a, float4 b) {
  half8 h;
  h[0] = (_Float16)a.x; h[1] = (_Float16)a.y; h[2] = (_Float16)a.z; h[3] = (_Float16)a.w;
  h[4] = (_Float16)b.x; h[5] = (_Float16)b.y; h[6] = (_Float16)b.z; h[7] = (_Float16)b.w;
  return h;
}

// ---------------------------------------------------------------------------
// C = X(4096x1024) * W^T(1024x1024) + bias.  f16 MFMA, fp32 accum.
// X dtype templated: float (raw inputs, converted during staging) or _Float16.
// W/bias are float (raw weights), converted during staging.
// mode 0: store fp16, permuted to [B, H, S, DH]   (QKV projections)
// mode 1: store FP32, row-major [M, D]            (output projection -> d_out)
// ---------------------------------------------------------------------------
template <typename XT>
__global__ __launch_bounds__(256) void gemm_proj(const XT* __restrict__ X,
                                                 const float* __restrict__ W,
                                                 const float* __restrict__ bias,
                                                 void* __restrict__ out, int mode) {
  __shared__ alignas(16) _Float16 As[128][40];   // +8 pad (odd # of 16B quads)
  __shared__ alignas(16) _Float16 Bs[128][40];

  const int t = threadIdx.x;
  const int lane = t & 63, wave = t >> 6;
  const int wr = wave >> 1, wc = wave & 1;          // wave's 64x64 quadrant
  const int m0 = blockIdx.y * 128, n0 = blockIdx.x * 128;
  const int fr = lane & 15;                          // A row / B col / C col
  const int fc = (lane >> 4) * 8;                    // frag k offset
  const int rg = (lane >> 4) * 4;                    // C row group

  floatx4 acc[4][4];
  for (int i = 0; i < 4; i++)
    for (int j = 0; j < 4; j++) acc[i][j] = (floatx4){0.f, 0.f, 0.f, 0.f};

  const int ar = t >> 1, ac = (t & 1) * 16;          // staging: row, col-half
  const XT*    ga = X + (size_t)(m0 + ar) * 1024 + ac;
  const float* gb = W + (size_t)(n0 + ar) * 1024 + ac;

  for (int k0 = 0; k0 < 1024; k0 += 32) {
    half8 a0, a1, b0, b1;
    if constexpr (sizeof(XT) == 4) {
      const float* p = (const float*)ga + k0;
      a0 = pack8(*(const float4*)(p),     *(const float4*)(p + 4));
      a1 = pack8(*(const float4*)(p + 8), *(const float4*)(p + 12));
    } else {
      const _Float16* p = (const _Float16*)ga + k0;
      a0 = *(const half8*)(p);
      a1 = *(const half8*)(p + 8);
    }
    {
      const float* p = gb + k0;
      b0 = pack8(*(const float4*)(p),     *(const float4*)(p + 4));
      b1 = pack8(*(const float4*)(p + 8), *(const float4*)(p + 12));
    }
    *(half8*)&As[ar][ac]     = a0;
    *(half8*)&As[ar][ac + 8] = a1;
    *(half8*)&Bs[ar][ac]     = b0;
    *(half8*)&Bs[ar][ac + 8] = b1;
    __syncthreads();

    half8 af[4], bw[4];
    for (int i = 0; i < 4; i++) {
      af[i] = *(const half8*)&As[wr * 64 + i * 16 + fr][fc];
      bw[i] = *(const half8*)&Bs[wc * 64 + i * 16 + fr][fc];
    }
    for (int i = 0; i < 4; i++)
      for (int j = 0; j < 4; j++)
        acc[i][j] = __builtin_amdgcn_mfma_f32_16x16x32_f16(af[i], bw[j], acc[i][j], 0, 0, 0);
    __syncthreads();
  }

  for (int i = 0; i < 4; i++)
    for (int j = 0; j < 4; j++) {
      int n = n0 + wc * 64 + j * 16 + fr;
      float bv = bias[n];
      for (int r = 0; r < 4; r++) {
        int m = m0 + wr * 64 + i * 16 + rg + r;
        float v = acc[i][j][r] + bv;
        if (mode == 0) {
          int bb = m >> 11, s = m & 2047, hh = n >> 6, d = n & 63;
          ((_Float16*)out)[(((size_t)(bb * NHEAD + hh)) * SEQ + s) * DH + d] = (_Float16)v;
        } else {
          ((float*)out)[(size_t)m * D_MODEL + n] = v;   // d_out is FP32
        }
      }
    }
}

// ---------------------------------------------------------------------------
// Flash attention. Q/K/V fp16 in [B, H, S, DH]. One block per (b, h, 128-q-tile).
// 4 waves; each wave owns 32 q rows (softmax state wave-local, 16-lane groups).
// LDS overlays: Qs (preload only) / Vt; Ks / Ps (barrier-separated).
// ---------------------------------------------------------------------------
__global__ __launch_bounds__(256) void attn_kernel(const _Float16* __restrict__ Qp,
                                                   const _Float16* __restrict__ Kp,
                                                   const _Float16* __restrict__ Vp,
                                                   const int* __restrict__ mask,
                                                   _Float16* __restrict__ ctx) {
  __shared__ alignas(16) char lds[18432 + 34816 + 512];   // 53.8 KB
  _Float16 (*Qs)[72]  = (_Float16(*)[72])lds;             // 128x72 (preload only)
  _Float16 (*Vt)[136] = (_Float16(*)[136])lds;            // 64x136 (overlays Qs)
  _Float16 (*Ks)[72]  = (_Float16(*)[72])(lds + 18432);   // 128x72
  _Float16 (*Ps)[136] = (_Float16(*)[136])(lds + 18432);  // 128x136 (overlays Ks)
  float* Ms = (float*)(lds + 18432 + 34816);              // 128 mask bias values

  const int b = blockIdx.z, h = blockIdx.y, q0 = blockIdx.x * 128;
  const int t = threadIdx.x, lane = t & 63, wave = t >> 6;
  const int fr = lane & 15, fc = (lane >> 4) * 8, rg = (lane >> 4) * 4;

  const _Float16* Qg = Qp + ((size_t)(b * NHEAD + h) * SEQ + q0) * DH;
  const _Float16* Kg = Kp + (size_t)(b * NHEAD + h) * SEQ * DH;
  const _Float16* Vg = Vp + (size_t)(b * NHEAD + h) * SEQ * DH;

  // ---- stage Q tile; preload Q fragments to registers ----
  {
    int r = t >> 1, c0 = (t & 1) * 32;
    const half8* g = (const half8*)(Qg + r * 64 + c0);
    for (int u = 0; u < 4; u++)
      *(half8*)&Qs[r][c0 + u * 8] = g[u];
  }
  __syncthreads();
  half8 qf[2][2];
  for (int mi = 0; mi < 2; mi++)
    for (int kk = 0; kk < 2; kk++)
      qf[mi][kk] = *(const half8*)&Qs[wave * 32 + mi * 16 + fr][kk * 32 + fc];
  __syncthreads();   // Qs region reused as Vt below

  float mrow[2][4], lrow[2][4];
  floatx4 oacc[2][4];
  for (int mi = 0; mi < 2; mi++)
    for (int r = 0; r < 4; r++) { mrow[mi][r] = -3.0e38f; lrow[mi][r] = 0.f; }
  for (int mi = 0; mi < 2; mi++)
    for (int dj = 0; dj < 4; dj++) oacc[mi][dj] = (floatx4){0.f, 0.f, 0.f, 0.f};

  for (int kt = 0; kt < SEQ / 128; kt++) {
    const int k0 = kt * 128;
    // ---- stage K tile, transposed V tile, mask bias ----
    {
      int r = t >> 1, c0 = (t & 1) * 32;
      const half8* gk = (const half8*)(Kg + (k0 + r) * 64 + c0);
      for (int u = 0; u < 4; u++)
        *(half8*)&Ks[r][c0 + u * 8] = gk[u];
      const half8* gv = (const half8*)(Vg + (k0 + r) * 64 + c0);
      half8 vv[4];
      for (int u = 0; u < 4; u++) vv[u] = gv[u];
      for (int u = 0; u < 4; u++)
        for (int j = 0; j < 8; j++) Vt[c0 + u * 8 + j][r] = vv[u][j];
      if (t < 128) Ms[t] = (float)mask[b * SEQ + k0 + t] * -1.0e9f;
    }
    __syncthreads();

    // ---- S = Q K^T (this wave's 32 q-rows x 128 k-cols) ----
    floatx4 sa[2][8];
    for (int mi = 0; mi < 2; mi++)
      for (int nj = 0; nj < 8; nj++) sa[mi][nj] = (floatx4){0.f, 0.f, 0.f, 0.f};
    for (int nj = 0; nj < 8; nj++)
      for (int kk = 0; kk < 2; kk++) {
        half8 kf = *(const half8*)&Ks[nj * 16 + fr][kk * 32 + fc];
        sa[0][nj] = __builtin_amdgcn_mfma_f32_16x16x32_f16(qf[0][kk], kf, sa[0][nj], 0, 0, 0);
        sa[1][nj] = __builtin_amdgcn_mfma_f32_16x16x32_f16(qf[1][kk], kf, sa[1][nj], 0, 0, 0);
      }
    __syncthreads();   // all waves done reading Ks; region becomes Ps

    // ---- scale + mask ----
    for (int nj = 0; nj < 8; nj++) {
      float mk = Ms[nj * 16 + fr];
      for (int mi = 0; mi < 2; mi++)
        for (int r = 0; r < 4; r++)
          sa[mi][nj][r] = sa[mi][nj][r] * 0.125f + mk;
    }

    // ---- online softmax (rows live across 16-lane groups) ----
    for (int mi = 0; mi < 2; mi++) {
      for (int r = 0; r < 4; r++) {
        float tm = sa[mi][0][r];
        for (int nj = 1; nj < 8; nj++) tm = fmaxf(tm, sa[mi][nj][r]);
        for (int off = 1; off < 16; off <<= 1) tm = fmaxf(tm, __shfl_xor(tm, off));
        float mnew = fmaxf(mrow[mi][r], tm);
        float alpha = __expf(mrow[mi][r] - mnew);
        mrow[mi][r] = mnew;
        float rs = 0.f;
        for (int nj = 0; nj < 8; nj++) {
          float p = __expf(sa[mi][nj][r] - mnew);
          sa[mi][nj][r] = p;
          rs += p;
        }
        for (int off = 1; off < 16; off <<= 1) rs += __shfl_xor(rs, off);
        lrow[mi][r] = lrow[mi][r] * alpha + rs;
        for (int dj = 0; dj < 4; dj++) oacc[mi][dj][r] *= alpha;
      }
    }

    // ---- write P to LDS (C-layout -> row-major) ----
    for (int mi = 0; mi < 2; mi++)
      for (int nj = 0; nj < 8; nj++)
        for (int r = 0; r < 4; r++)
          Ps[wave * 32 + mi * 16 + rg + r][nj * 16 + fr] = (_Float16)sa[mi][nj][r];
    __syncthreads();   // P visible (and fence for the LDS round-trip)

    // ---- O += P V ----
    for (int kk = 0; kk < 4; kk++) {
      half8 pf[2], vf[4];
      for (int mi = 0; mi < 2; mi++)
        pf[mi] = *(const half8*)&Ps[wave * 32 + mi * 16 + fr][kk * 32 + fc];
      for (int dj = 0; dj < 4; dj++)
        vf[dj] = *(const half8*)&Vt[dj * 16 + fr][kk * 32 + fc];
      for (int mi = 0; mi < 2; mi++)
        for (int dj = 0; dj < 4; dj++)
          oacc[mi][dj] = __builtin_amdgcn_mfma_f32_16x16x32_f16(pf[mi], vf[dj], oacc[mi][dj], 0, 0, 0);
    }
    __syncthreads();   // protect Ks/Vt/Ps before next staging
  }

  // ---- epilogue: O / l -> ctx[b, s, h*64 + d] (fp16, GEMM-ready layout) ----
  for (int mi = 0; mi < 2; mi++)
    for (int r = 0; r < 4; r++) {
      float inv = 1.0f / lrow[mi][r];
      int qrow = q0 + wave * 32 + mi * 16 + rg + r;
      _Float16* o = ctx + ((size_t)b * SEQ + qrow) * D_MODEL + h * DH;
      for (int dj = 0; dj < 4; dj++)
        o[dj * 16 + fr] = (_Float16)(oacc[mi][dj][r] * inv);
    }
}

// ---------------------------------------------------------------------------
extern "C" void kernel_launch(void* const* d_in, const int* in_sizes, int n_in,
                              void* d_out, int out_size, void* d_ws, size_t ws_size,
                              hipStream_t stream) {
  // All float tensors are float32 (per the reference); mask is int32.
  // d_out is float32 (reference output dtype).
  const float* query = (const float*)d_in[0];
  const float* key   = (const float*)d_in[1];
  const float* value = (const float*)d_in[2];
  const int*   mask  = (const int*)d_in[3];
  const float* Wq = (const float*)d_in[4];
  const float* bq = (const float*)d_in[5];
  const float* Wk = (const float*)d_in[6];
  const float* bk = (const float*)d_in[7];
  const float* Wv = (const float*)d_in[8];
  const float* bv = (const float*)d_in[9];
  const float* Wo = (const float*)d_in[10];
  const float* bo = (const float*)d_in[11];

  char* ws = (char*)d_ws;
  // total ws footprint: 32 MB
  _Float16* Qp  = (_Float16*)(ws);                            // 8 MB [B,H,S,DH]
  _Float16* Kp  = (_Float16*)(ws + (size_t)8  * 1024 * 1024);
  _Float16* Vp  = (_Float16*)(ws + (size_t)16 * 1024 * 1024);
  _Float16* ctx = (_Float16*)(ws + (size_t)24 * 1024 * 1024); // 8 MB [M, D]

  dim3 ggrid(D_MODEL / 128, M_TOT / 128);  // (8, 32)
  gemm_proj<float><<<ggrid, 256, 0, stream>>>(query, Wq, bq, Qp, 0);
  gemm_proj<float><<<ggrid, 256, 0, stream>>>(key,   Wk, bk, Kp, 0);
  gemm_proj<float><<<ggrid, 256, 0, stream>>>(value, Wv, bv, Vp, 0);

  attn_kernel<<<dim3(SEQ / 128, NHEAD, BATCH), 256, 0, stream>>>(Qp, Kp, Vp, mask, ctx);

  gemm_proj<_Float16><<<ggrid, 256, 0, stream>>>(ctx, Wo, bo, d_out, 1);
}

// Round 5
// 282.498 us; speedup vs baseline: 1.4295x; 1.4295x over previous
//
#include <hip/hip_runtime.h>

typedef _Float16 half8 __attribute__((ext_vector_type(8)));
typedef float floatx4 __attribute__((ext_vector_type(4)));

#define D_MODEL 1024
#define NHEAD   16
#define DH      64
#define BATCH   2
#define SEQ     2048
#define M_TOT   4096   // BATCH*SEQ

// async global->LDS DMA, 16B per lane. lds base is WAVE-UNIFORM; HW adds lane*16.
#define GLD_LDS16(g, l)                                                          \
  __builtin_amdgcn_global_load_lds(                                              \
      (const __attribute__((address_space(1))) void*)(g),                        \
      (__attribute__((address_space(3))) void*)(l), 16, 0, 0)

// ---------------------------------------------------------------------------
// One-shot fp32 -> fp16 conversion of q,k,v (4M elems each) and Wq..Wo (1M each).
// blocks 0..6143: q/k/v (2048 blocks each); 6144..8191: weights (512 each).
// ---------------------------------------------------------------------------
__global__ __launch_bounds__(256) void cvt_all(const float* __restrict__ q,
                                               const float* __restrict__ k,
                                               const float* __restrict__ v,
                                               const float* __restrict__ wq,
                                               const float* __restrict__ wk,
                                               const float* __restrict__ wv,
                                               const float* __restrict__ wo,
                                               _Float16* __restrict__ Xall,
                                               _Float16* __restrict__ Wall) {
  int bid = blockIdx.x;
  const float* src;
  _Float16* dst;
  if (bid < 6144) {
    int tsr = bid >> 11;
    src = (tsr == 0) ? q : (tsr == 1) ? k : v;
    dst = Xall + (size_t)tsr * 4194304;
    bid &= 2047;
  } else {
    int w = (bid - 6144) >> 9;
    src = (w == 0) ? wq : (w == 1) ? wk : (w == 2) ? wv : wo;
    dst = Wall + (size_t)w * 1048576;
    bid = (bid - 6144) & 511;
  }
  int off = bid * 2048 + threadIdx.x * 8;
  float4 a = *(const float4*)(src + off);
  float4 b = *(const float4*)(src + off + 4);
  half8 h;
  h[0] = (_Float16)a.x; h[1] = (_Float16)a.y; h[2] = (_Float16)a.z; h[3] = (_Float16)a.w;
  h[4] = (_Float16)b.x; h[5] = (_Float16)b.y; h[6] = (_Float16)b.z; h[7] = (_Float16)b.w;
  *(half8*)(dst + off) = h;
}

// ---------------------------------------------------------------------------
// Fused QKV projection: C_z = X_z * W_z^T + b_z, z = 0,1,2 (q,k,v).
// 128x128 tile, BK=32, global_load_lds staging, f16 MFMA, fp32 accum.
// Output permuted to [B, H, S, DH] fp16.
// ---------------------------------------------------------------------------
__global__ __launch_bounds__(256) void gemm_qkv(const _Float16* __restrict__ Xall,
                                                const _Float16* __restrict__ Wall,
                                                const float* __restrict__ bq,
                                                const float* __restrict__ bk,
                                                const float* __restrict__ bv,
                                                _Float16* __restrict__ Obase) {
  __shared__ alignas(16) _Float16 As[128][32];   // unpadded: global_load_lds layout
  __shared__ alignas(16) _Float16 Bs[128][32];

  const int z = blockIdx.z;
  const _Float16* X = Xall + (size_t)z * 4194304;
  const _Float16* W = Wall + (size_t)z * 1048576;
  const float* bias = (z == 0) ? bq : (z == 1) ? bk : bv;
  _Float16* out = Obase + (size_t)z * 4194304;

  const int t = threadIdx.x, lane = t & 63, wave = t >> 6;
  const int wr = wave >> 1, wc = wave & 1;
  const int m0 = blockIdx.y * 128, n0 = blockIdx.x * 128;
  const int fr = lane & 15, fc = (lane >> 4) * 8, rg = (lane >> 4) * 4;

  floatx4 acc[4][4];
  for (int i = 0; i < 4; i++)
    for (int j = 0; j < 4; j++) acc[i][j] = (floatx4){0.f, 0.f, 0.f, 0.f};

  const int srow = lane >> 2, scol = (lane & 3) * 8;     // 16 rows x 32B per instr
  const _Float16* gA0 = X + (size_t)(m0 + wave * 32 + srow) * 1024 + scol;
  const _Float16* gA1 = gA0 + 16 * 1024;
  const _Float16* gB0 = W + (size_t)(n0 + wave * 32 + srow) * 1024 + scol;
  const _Float16* gB1 = gB0 + 16 * 1024;
  _Float16* lA0 = &As[wave * 32][0];
  _Float16* lA1 = &As[wave * 32 + 16][0];
  _Float16* lB0 = &Bs[wave * 32][0];
  _Float16* lB1 = &Bs[wave * 32 + 16][0];

  for (int k0 = 0; k0 < 1024; k0 += 32) {
    GLD_LDS16(gA0 + k0, lA0);
    GLD_LDS16(gA1 + k0, lA1);
    GLD_LDS16(gB0 + k0, lB0);
    GLD_LDS16(gB1 + k0, lB1);
    __syncthreads();

    half8 af[4], bw[4];
    for (int i = 0; i < 4; i++) {
      af[i] = *(const half8*)&As[wr * 64 + i * 16 + fr][fc];
      bw[i] = *(const half8*)&Bs[wc * 64 + i * 16 + fr][fc];
    }
    for (int i = 0; i < 4; i++)
      for (int j = 0; j < 4; j++)
        acc[i][j] = __builtin_amdgcn_mfma_f32_16x16x32_f16(af[i], bw[j], acc[i][j], 0, 0, 0);
    __syncthreads();
  }

  // epilogue: permute to [B, H, S, DH] fp16
  for (int i = 0; i < 4; i++)
    for (int j = 0; j < 4; j++) {
      int n = n0 + wc * 64 + j * 16 + fr;
      float bv2 = bias[n];
      int hh = n >> 6, d = n & 63;
      for (int r = 0; r < 4; r++) {
        int m = m0 + wr * 64 + i * 16 + rg + r;
        int bb = m >> 11, s = m & 2047;
        out[(((size_t)(bb * NHEAD + hh)) * SEQ + s) * DH + d] =
            (_Float16)(acc[i][j][r] + bv2);
      }
    }
}

// ---------------------------------------------------------------------------
// Output projection: d_out(f32) = ctx(4096x1024 f16) * Wo^T + bo.
// 128x64 tile (512 blocks = 2/CU), BK=32, global_load_lds staging.
// ---------------------------------------------------------------------------
__global__ __launch_bounds__(256) void gemm_wo(const _Float16* __restrict__ ctx,
                                               const _Float16* __restrict__ W,
                                               const float* __restrict__ bias,
                                               float* __restrict__ out) {
  __shared__ alignas(16) _Float16 As[128][32];
  __shared__ alignas(16) _Float16 Bs[64][32];

  const int t = threadIdx.x, lane = t & 63, wave = t >> 6;
  const int m0 = blockIdx.y * 128, n0 = blockIdx.x * 64;
  const int fr = lane & 15, fc = (lane >> 4) * 8, rg = (lane >> 4) * 4;

  floatx4 acc[2][4];
  for (int i = 0; i < 2; i++)
    for (int j = 0; j < 4; j++) acc[i][j] = (floatx4){0.f, 0.f, 0.f, 0.f};

  const int srow = lane >> 2, scol = (lane & 3) * 8;
  const _Float16* gA0 = ctx + (size_t)(m0 + wave * 32 + srow) * 1024 + scol;
  const _Float16* gA1 = gA0 + 16 * 1024;
  const _Float16* gB0 = W + (size_t)(n0 + wave * 16 + srow) * 1024 + scol;
  _Float16* lA0 = &As[wave * 32][0];
  _Float16* lA1 = &As[wave * 32 + 16][0];
  _Float16* lB0 = &Bs[wave * 16][0];

  for (int k0 = 0; k0 < 1024; k0 += 32) {
    GLD_LDS16(gA0 + k0, lA0);
    GLD_LDS16(gA1 + k0, lA1);
    GLD_LDS16(gB0 + k0, lB0);
    __syncthreads();

    half8 af[2], bw[4];
    for (int i = 0; i < 2; i++)
      af[i] = *(const half8*)&As[wave * 32 + i * 16 + fr][fc];
    for (int j = 0; j < 4; j++)
      bw[j] = *(const half8*)&Bs[j * 16 + fr][fc];
    for (int i = 0; i < 2; i++)
      for (int j = 0; j < 4; j++)
        acc[i][j] = __builtin_amdgcn_mfma_f32_16x16x32_f16(af[i], bw[j], acc[i][j], 0, 0, 0);
    __syncthreads();
  }

  for (int i = 0; i < 2; i++)
    for (int j = 0; j < 4; j++) {
      int n = n0 + j * 16 + fr;
      float bv2 = bias[n];
      for (int r = 0; r < 4; r++) {
        int m = m0 + wave * 32 + i * 16 + rg + r;
        out[(size_t)m * D_MODEL + n] = acc[i][j][r] + bv2;
      }
    }
}

// ---------------------------------------------------------------------------
// Flash attention (unchanged from R4's verified version).
// ---------------------------------------------------------------------------
__global__ __launch_bounds__(256) void attn_kernel(const _Float16* __restrict__ Qp,
                                                   const _Float16* __restrict__ Kp,
                                                   const _Float16* __restrict__ Vp,
                                                   const int* __restrict__ mask,
                                                   _Float16* __restrict__ ctx) {
  __shared__ alignas(16) char lds[18432 + 34816 + 512];   // 53.8 KB
  _Float16 (*Qs)[72]  = (_Float16(*)[72])lds;             // 128x72 (preload only)
  _Float16 (*Vt)[136] = (_Float16(*)[136])lds;            // 64x136 (overlays Qs)
  _Float16 (*Ks)[72]  = (_Float16(*)[72])(lds + 18432);   // 128x72
  _Float16 (*Ps)[136] = (_Float16(*)[136])(lds + 18432);  // 128x136 (overlays Ks)
  float* Ms = (float*)(lds + 18432 + 34816);              // 128 mask bias values

  const int b = blockIdx.z, h = blockIdx.y, q0 = blockIdx.x * 128;
  const int t = threadIdx.x, lane = t & 63, wave = t >> 6;
  const int fr = lane & 15, fc = (lane >> 4) * 8, rg = (lane >> 4) * 4;

  const _Float16* Qg = Qp + ((size_t)(b * NHEAD + h) * SEQ + q0) * DH;
  const _Float16* Kg = Kp + (size_t)(b * NHEAD + h) * SEQ * DH;
  const _Float16* Vg = Vp + (size_t)(b * NHEAD + h) * SEQ * DH;

  {
    int r = t >> 1, c0 = (t & 1) * 32;
    const half8* g = (const half8*)(Qg + r * 64 + c0);
    for (int u = 0; u < 4; u++)
      *(half8*)&Qs[r][c0 + u * 8] = g[u];
  }
  __syncthreads();
  half8 qf[2][2];
  for (int mi = 0; mi < 2; mi++)
    for (int kk = 0; kk < 2; kk++)
      qf[mi][kk] = *(const half8*)&Qs[wave * 32 + mi * 16 + fr][kk * 32 + fc];
  __syncthreads();

  float mrow[2][4], lrow[2][4];
  floatx4 oacc[2][4];
  for (int mi = 0; mi < 2; mi++)
    for (int r = 0; r < 4; r++) { mrow[mi][r] = -3.0e38f; lrow[mi][r] = 0.f; }
  for (int mi = 0; mi < 2; mi++)
    for (int dj = 0; dj < 4; dj++) oacc[mi][dj] = (floatx4){0.f, 0.f, 0.f, 0.f};

  for (int kt = 0; kt < SEQ / 128; kt++) {
    const int k0 = kt * 128;
    {
      int r = t >> 1, c0 = (t & 1) * 32;
      const half8* gk = (const half8*)(Kg + (k0 + r) * 64 + c0);
      for (int u = 0; u < 4; u++)
        *(half8*)&Ks[r][c0 + u * 8] = gk[u];
      const half8* gv = (const half8*)(Vg + (k0 + r) * 64 + c0);
      half8 vv[4];
      for (int u = 0; u < 4; u++) vv[u] = gv[u];
      for (int u = 0; u < 4; u++)
        for (int j = 0; j < 8; j++) Vt[c0 + u * 8 + j][r] = vv[u][j];
      if (t < 128) Ms[t] = (float)mask[b * SEQ + k0 + t] * -1.0e9f;
    }
    __syncthreads();

    floatx4 sa[2][8];
    for (int mi = 0; mi < 2; mi++)
      for (int nj = 0; nj < 8; nj++) sa[mi][nj] = (floatx4){0.f, 0.f, 0.f, 0.f};
    for (int nj = 0; nj < 8; nj++)
      for (int kk = 0; kk < 2; kk++) {
        half8 kf = *(const half8*)&Ks[nj * 16 + fr][kk * 32 + fc];
        sa[0][nj] = __builtin_amdgcn_mfma_f32_16x16x32_f16(qf[0][kk], kf, sa[0][nj], 0, 0, 0);
        sa[1][nj] = __builtin_amdgcn_mfma_f32_16x16x32_f16(qf[1][kk], kf, sa[1][nj], 0, 0, 0);
      }
    __syncthreads();

    for (int nj = 0; nj < 8; nj++) {
      float mk = Ms[nj * 16 + fr];
      for (int mi = 0; mi < 2; mi++)
        for (int r = 0; r < 4; r++)
          sa[mi][nj][r] = sa[mi][nj][r] * 0.125f + mk;
    }

    for (int mi = 0; mi < 2; mi++) {
      for (int r = 0; r < 4; r++) {
        float tm = sa[mi][0][r];
        for (int nj = 1; nj < 8; nj++) tm = fmaxf(tm, sa[mi][nj][r]);
        for (int off = 1; off < 16; off <<= 1) tm = fmaxf(tm, __shfl_xor(tm, off));
        float mnew = fmaxf(mrow[mi][r], tm);
        float alpha = __expf(mrow[mi][r] - mnew);
        mrow[mi][r] = mnew;
        float rs = 0.f;
        for (int nj = 0; nj < 8; nj++) {
          float p = __expf(sa[mi][nj][r] - mnew);
          sa[mi][nj][r] = p;
          rs += p;
        }
        for (int off = 1; off < 16; off <<= 1) rs += __shfl_xor(rs, off);
        lrow[mi][r] = lrow[mi][r] * alpha + rs;
        for (int dj = 0; dj < 4; dj++) oacc[mi][dj][r] *= alpha;
      }
    }

    for (int mi = 0; mi < 2; mi++)
      for (int nj = 0; nj < 8; nj++)
        for (int r = 0; r < 4; r++)
          Ps[wave * 32 + mi * 16 + rg + r][nj * 16 + fr] = (_Float16)sa[mi][nj][r];
    __syncthreads();

    for (int kk = 0; kk < 4; kk++) {
      half8 pf[2], vf[4];
      for (int mi = 0; mi < 2; mi++)
        pf[mi] = *(const half8*)&Ps[wave * 32 + mi * 16 + fr][kk * 32 + fc];
      for (int dj = 0; dj < 4; dj++)
        vf[dj] = *(const half8*)&Vt[dj * 16 + fr][kk * 32 + fc];
      for (int mi = 0; mi < 2; mi++)
        for (int dj = 0; dj < 4; dj++)
          oacc[mi][dj] = __builtin_amdgcn_mfma_f32_16x16x32_f16(pf[mi], vf[dj], oacc[mi][dj], 0, 0, 0);
    }
    __syncthreads();
  }

  for (int mi = 0; mi < 2; mi++)
    for (int r = 0; r < 4; r++) {
      float inv = 1.0f / lrow[mi][r];
      int qrow = q0 + wave * 32 + mi * 16 + rg + r;
      _Float16* o = ctx + ((size_t)b * SEQ + qrow) * D_MODEL + h * DH;
      for (int dj = 0; dj < 4; dj++)
        o[dj * 16 + fr] = (_Float16)(oacc[mi][dj][r] * inv);
    }
}

// ---------------------------------------------------------------------------
extern "C" void kernel_launch(void* const* d_in, const int* in_sizes, int n_in,
                              void* d_out, int out_size, void* d_ws, size_t ws_size,
                              hipStream_t stream) {
  const float* query = (const float*)d_in[0];
  const float* key   = (const float*)d_in[1];
  const float* value = (const float*)d_in[2];
  const int*   mask  = (const int*)d_in[3];
  const float* Wq = (const float*)d_in[4];
  const float* bq = (const float*)d_in[5];
  const float* Wk = (const float*)d_in[6];
  const float* bk = (const float*)d_in[7];
  const float* Wv = (const float*)d_in[8];
  const float* bv = (const float*)d_in[9];
  const float* Wo = (const float*)d_in[10];
  const float* bo = (const float*)d_in[11];

  char* ws = (char*)d_ws;
  // ws layout (64 MB total):
  _Float16* Xall = (_Float16*)(ws);                            // 24 MB: q,k,v f16
  _Float16* Wall = (_Float16*)(ws + (size_t)24 * 1024 * 1024); //  8 MB: Wq,Wk,Wv,Wo f16
  _Float16* Qp   = (_Float16*)(ws + (size_t)32 * 1024 * 1024); // 24 MB: Q,K,V permuted
  _Float16* ctx  = (_Float16*)(ws + (size_t)56 * 1024 * 1024); //  8 MB

  _Float16* Kp = Qp + (size_t)4194304;
  _Float16* Vp = Qp + (size_t)8388608;

  cvt_all<<<8192, 256, 0, stream>>>(query, key, value, Wq, Wk, Wv, Wo, Xall, Wall);

  gemm_qkv<<<dim3(8, 32, 3), 256, 0, stream>>>(Xall, Wall, bq, bk, bv, Qp);

  attn_kernel<<<dim3(SEQ / 128, NHEAD, BATCH), 256, 0, stream>>>(Qp, Kp, Vp, mask, ctx);

  gemm_wo<<<dim3(16, 32), 256, 0, stream>>>(ctx, Wall + (size_t)3 * 1048576, bo, (float*)d_out);
}